// Round 3
// baseline (916.727 us; speedup 1.0000x reference)
//
#include <hip/hip_runtime.h>
#include <math.h>

// ---------------------------------------------------------------------------
// SwinV2-style block (DIM=192, HEADS=6, WS=8, SHIFT=4) on MI355X.
// Round 3: GEMM v2 — 256x96 tiles, A direct global->reg (no LDS), B-only
// LDS staging in k-plane layout (conflict-free b128 frag reads), 1 barrier
// per K-step, conv squeeze fused into conv2 epilogue.
// ---------------------------------------------------------------------------

typedef unsigned short u16;
typedef __attribute__((ext_vector_type(8))) short short8;
typedef __attribute__((ext_vector_type(4))) float f32x4;

#define DI static __device__ __forceinline__

DI float b2f(u16 u){ union{unsigned u; float f;} v; v.u = ((unsigned)u)<<16; return v.f; }
DI u16 f2b(float f){ union{float f; unsigned u;} v; v.f = f; unsigned r = v.u + 0x7fffu + ((v.u>>16)&1u); return (u16)(r>>16); }
DI float gelu_f(float x){ return 0.5f*x*(1.0f+erff(x*0.7071067811865475f)); }

// ---------------- LayerNorm: f32 in -> bf16 out (row = 192 ch) -------------
__global__ __launch_bounds__(256) void ln_k(const float* __restrict__ in,
    const float* __restrict__ w, const float* __restrict__ b, u16* __restrict__ out)
{
  const int row  = blockIdx.x*4 + (threadIdx.x>>6);
  const int lane = threadIdx.x & 63;
  const float* r = in + (long)row*192;
  float v0 = r[lane], v1 = r[lane+64], v2 = r[lane+128];
  float s = v0+v1+v2;
  #pragma unroll
  for (int m=1;m<64;m<<=1) s += __shfl_xor(s, m);
  float mu = s*(1.0f/192.0f);
  float d0=v0-mu, d1=v1-mu, d2=v2-mu;
  float q = d0*d0+d1*d1+d2*d2;
  #pragma unroll
  for (int m=1;m<64;m<<=1) q += __shfl_xor(q, m);
  float rstd = rsqrtf(q*(1.0f/192.0f)+1e-5f);
  u16* o = out + (long)row*192;
  o[lane]     = f2b(d0*rstd*w[lane]    +b[lane]);
  o[lane+64]  = f2b(d1*rstd*w[lane+64] +b[lane+64]);
  o[lane+128] = f2b(d2*rstd*w[lane+128]+b[lane+128]);
}

// ------------- weight prep: f32->bf16 + conv re-layout + qkv bias ----------
__global__ __launch_bounds__(256) void prep_k(
    const float* __restrict__ qkv_w, const float* __restrict__ q_bias,
    const float* __restrict__ v_bias, const float* __restrict__ proj_w,
    const float* __restrict__ fc1_w, const float* __restrict__ fc2_w,
    const float* __restrict__ cab1_w, const float* __restrict__ cab2_w,
    const float* __restrict__ lgs,
    float* __restrict__ qkvbias, u16* __restrict__ wqkv, u16* __restrict__ wproj,
    u16* __restrict__ wfc1, u16* __restrict__ wfc2, u16* __restrict__ wt1,
    u16* __restrict__ wt2, float* __restrict__ scale6)
{
  int o = blockIdx.x*256 + threadIdx.x;
  if (o < 576){ qkvbias[o] = (o<192)? q_bias[o] : ((o<384)? 0.f : v_bias[o-384]); return; }
  o -= 576;
  if (o < 110592){ wqkv[o] = f2b(qkv_w[o]); return; } o -= 110592;
  if (o < 36864){ wproj[o] = f2b(proj_w[o]); return; } o -= 36864;
  if (o < 147456){ wfc1[o] = f2b(fc1_w[o]); return; } o -= 147456;
  if (o < 147456){ wfc2[o] = f2b(fc2_w[o]); return; } o -= 147456;
  if (o < 110592){ // wt1[s][oc(64)][ic(192)] <- cab1_w[oc][ic][kh][kw]
    int s = o/12288, r = o%12288, oc = r/192, ic = r%192, kh = s/3, kw = s%3;
    wt1[o] = f2b(cab1_w[((oc*192+ic)*3+kh)*3+kw]); return; } o -= 110592;
  if (o < 110592){ // wt2[s][oc(192)][ic(64)] <- cab2_w[oc][ic][kh][kw]
    int s = o/12288, r = o%12288, oc = r/64, ic = r%64, kh = s/3, kw = s%3;
    wt2[o] = f2b(cab2_w[((oc*64+ic)*3+kh)*3+kw]); return; } o -= 110592;
  if (o < 6){ scale6[o] = expf(fminf(lgs[o], logf(100.f))); }
}

// ---- CPB MLP -> rpbL in MFMA C-fragment order: [h][nQ][mK][lane][i] -------
__global__ __launch_bounds__(256) void rpb_k(const float* __restrict__ w1,
    const float* __restrict__ b1, const float* __restrict__ w2, float* __restrict__ rpbL)
{
  __shared__ float hb[225*6];
  const int tid = threadIdx.x;
  if (tid < 225){
    int di = tid/15, dj = tid%15;
    float vi = (di-7)*(8.0f/7.0f), vj = (dj-7)*(8.0f/7.0f);
    float t0 = (vi==0.f)?0.f:copysignf(log2f(fabsf(vi)+1.f)*(1.f/3.f), vi);
    float t1 = (vj==0.f)?0.f:copysignf(log2f(fabsf(vj)+1.f)*(1.f/3.f), vj);
    float acc[6] = {0,0,0,0,0,0};
    for (int hd=0; hd<512; ++hd){
      float a = fmaxf(t0*w1[hd*2] + t1*w1[hd*2+1] + b1[hd], 0.f);
      #pragma unroll
      for (int h=0;h<6;++h) acc[h] += a*w2[h*512+hd];
    }
    #pragma unroll
    for (int h=0;h<6;++h) hb[tid*6+h] = acc[h];
  }
  __syncthreads();
  for (int o = tid; o < 24576; o += 256){
    int i = o&3, lane = (o>>2)&63, mK = (o>>8)&3, nQ = (o>>10)&3, h = o>>12;
    int q = nQ*16 + (lane&15), k = mK*16 + (lane>>4)*4 + i;
    int idx = ((q>>3)-(k>>3)+7)*15 + ((q&7)-(k&7)+7);
    rpbL[o] = 16.0f/(1.0f+expf(-hb[idx*6+h]));
  }
}

// ---------------- GEMM v2: out(M,NN) = A(M,K) @ W(NN,K)^T ------------------
// Tile 256 x NT, 4 waves (wave = 64 rows x NT cols, M_rep=4, N_rep=NT/16).
// A: direct global->reg per lane (pipelined 1 K-step ahead, conv-masked).
// B: reg-staged dbuf LDS, plane layout [g][row] -> lane-consecutive b128.
// EPI: 0 qkv->bf16  1 gelu->bf16 (conv1)  2 ->f32 + fused squeeze (conv2)
//      3 proj merge->f32  4 gelu->bf16 (fc1)  5 accumulate into outf (fc2)
template<int EPI, int SEGS, int KSEG, int NN, int NT>
__global__ __launch_bounds__(256, 2) void gemm2_k(
    const u16* __restrict__ A, const u16* __restrict__ W,
    const float* __restrict__ bias, const float* __restrict__ resx,
    const float* __restrict__ c2in, const float* __restrict__ sgate,
    float* __restrict__ outf, u16* __restrict__ outb, float* __restrict__ ssum)
{
  constexpr int STEPS = KSEG/32, TOT = SEGS*STEPS, NR = NT/16;
  constexpr int BP = (NT*4 + 255)/256;           // B staging passes
  __shared__ __align__(16) u16 Bs[2][4*(NT+1)*8];
  const int tid = threadIdx.x, w = tid>>6, lane = tid&63;
  const int l15 = lane&15, g = lane>>4;
  const int m0 = blockIdx.y*256, n0 = blockIdx.x*NT;
  const int bc = tid&3, br = tid>>2;

  int abb[4], ayy[4], axx[4]; long abase[4];
  #pragma unroll
  for (int mr=0; mr<4; ++mr){
    int r = m0 + w*64 + mr*16 + l15;
    if constexpr (SEGS>1){ abb[mr]=r>>14; ayy[mr]=(r>>7)&127; axx[mr]=r&127; abase[mr]=0; }
    else { abase[mr] = (long)r*KSEG; abb[mr]=ayy[mr]=axx[mr]=0; }
  }
  f32x4 acc[4][NR];
  #pragma unroll
  for (int a=0;a<4;++a)
    #pragma unroll
    for (int b=0;b<NR;++b) acc[a][b] = (f32x4){0.f,0.f,0.f,0.f};

  short8 a0[4], a1[4], breg[BP];

  #define LOADA(ks,dst) { \
    if constexpr (SEGS>1){ \
      const int seg_=(ks)/STEPS, kin_=((ks)-seg_*STEPS)*32; \
      const int dy_=seg_/3-1, dx_=seg_%3-1; \
      _Pragma("unroll") \
      for (int mr=0;mr<4;++mr){ \
        const int sy_=ayy[mr]+dy_, sx_=axx[mr]+dx_; \
        short8 v_={0,0,0,0,0,0,0,0}; \
        if ((unsigned)sy_<128u && (unsigned)sx_<128u) \
          v_ = *(const short8*)(A + ((long)(((abb[mr]<<7)|sy_)<<7 | sx_))*KSEG + kin_ + g*8); \
        dst[mr]=v_; } \
    } else { \
      _Pragma("unroll") \
      for (int mr=0;mr<4;++mr) dst[mr] = *(const short8*)(A + abase[mr] + (ks)*32 + g*8); \
    } }

  #define LOADB(ks) { \
    const int seg_=(ks)/STEPS, kin_=((ks)-seg_*STEPS)*32; \
    const u16* Wb_ = W + (SEGS>1 ? (long)seg_*NN*KSEG : 0L) + (long)n0*KSEG + kin_ + bc*8; \
    _Pragma("unroll") \
    for (int p=0;p<BP;++p){ const int row_=br+p*64; \
      if (row_<NT) breg[p] = *(const short8*)(Wb_ + (long)row_*KSEG); } }

  #define WRITEB(buf) { \
    _Pragma("unroll") \
    for (int p=0;p<BP;++p){ const int row_=br+p*64; \
      if (row_<NT) *(short8*)(&Bs[buf][(bc*(NT+1)+row_)*8]) = breg[p]; } }

  #define COMPUTE(buf,aR) { \
    short8 bf_[NR]; \
    _Pragma("unroll") \
    for (int nr=0;nr<NR;++nr) bf_[nr] = *(const short8*)(&Bs[buf][(g*(NT+1)+nr*16+l15)*8]); \
    _Pragma("unroll") \
    for (int mr=0;mr<4;++mr) \
      _Pragma("unroll") \
      for (int nr=0;nr<NR;++nr) \
        acc[mr][nr] = __builtin_amdgcn_mfma_f32_16x16x32_bf16(aR[mr], bf_[nr], acc[mr][nr], 0, 0, 0); }

  LOADB(0); LOADA(0, a0);
  WRITEB(0);
  __syncthreads();
  for (int ks=0; ks<TOT; ks+=2){
    LOADB(ks+1); LOADA(ks+1, a1);
    COMPUTE(0, a0);
    WRITEB(1);
    __syncthreads();
    const bool more = (ks+2) < TOT;
    if (more){ LOADB(ks+2); LOADA(ks+2, a0); }
    COMPUTE(1, a1);
    if (more){ WRITEB(0); }
    __syncthreads();
  }
  #undef LOADA
  #undef LOADB
  #undef WRITEB
  #undef COMPUTE

  // ---- epilogue ----
  float cs[NR];
  #pragma unroll
  for (int nr=0;nr<NR;++nr) cs[nr]=0.f;
  #pragma unroll
  for (int mr=0;mr<4;++mr){
    #pragma unroll
    for (int nr=0;nr<NR;++nr){
      const int gcol = n0 + nr*16 + l15;
      const float bcol = bias[gcol];
      #pragma unroll
      for (int i=0;i<4;++i){
        const int grow = m0 + w*64 + mr*16 + g*4 + i;
        const long o = (long)grow*NN + gcol;
        float v = acc[mr][nr][i] + bcol;
        if constexpr (EPI==0){ outb[o] = f2b(v); }
        else if constexpr (EPI==1){ outb[o] = f2b(gelu_f(v)); }
        else if constexpr (EPI==2){ outf[o] = v; cs[nr] += v; }
        else if constexpr (EPI==3){
          outf[o] = v + resx[o] + 0.01f*c2in[o]*sgate[(grow>>14)*192 + gcol];
        }
        else if constexpr (EPI==4){ outb[o] = f2b(gelu_f(v)); }
        else { outf[o] = outf[o] + v; }
      }
    }
  }
  if constexpr (EPI==2){   // fused squeeze: per-col sum over this block's 256 rows
    #pragma unroll
    for (int nr=0;nr<NR;++nr){
      float s = cs[nr];
      s += __shfl_xor(s,16); s += __shfl_xor(s,32);
      if (lane < 16) atomicAdd(&ssum[(m0>>14)*192 + n0 + nr*16 + lane], s);
    }
  }
}

// ------------- SE MLP ------------------------------------------------------
__global__ __launch_bounds__(256) void se_k(const float* __restrict__ ssum,
    const float* __restrict__ ca1w, const float* __restrict__ ca1b,
    const float* __restrict__ ca2w, const float* __restrict__ ca2b,
    float* __restrict__ sgate)
{
  __shared__ float hid[48];
  const int tid = threadIdx.x;
  if (tid < 48){
    int b = tid/6, cs = tid%6;
    float a = ca1b[cs];
    for (int c=0;c<192;++c) a += ssum[b*192+c]*(1.f/16384.f)*ca1w[cs*192+c];
    hid[tid] = fmaxf(a, 0.f);
  }
  __syncthreads();
  for (int o = tid; o < 1536; o += 256){
    int b = o/192, c = o%192;
    float a = ca2b[c];
    #pragma unroll
    for (int cs=0;cs<6;++cs) a += hid[b*6+cs]*ca2w[c*6+cs];
    sgate[o] = 1.f/(1.f+expf(-a));
  }
}

// ---------- MFMA windowed attention: 1 wave = 1 (window, head) -------------
__global__ __launch_bounds__(256) void attn_k(const u16* __restrict__ qkv,
    const float* __restrict__ rpbL, const float* __restrict__ scale6,
    u16* __restrict__ aout)
{
  __shared__ int  lidx_s[4][64];
  __shared__ char region_s[4][64];
  __shared__ __align__(16) u16 p_s[4][64*72];
  const int tid = threadIdx.x, w = tid>>6, lane = tid&63;
  const int task = blockIdx.x*4 + w;
  const int win = task/6, h = task - win*6;
  const int b = win>>8, wn = win&255, wy = wn>>4, wx = wn&15;
  {
    int i = lane>>3, j = lane&7;
    int hs = wy*8+i, ws = wx*8+j;
    lidx_s[w][lane] = (b<<14) | (((hs+4)&127)<<7) | ((ws+4)&127);
    int hb = hs<120?0:(hs<124?1:2), wb = ws<120?0:(ws<124?1:2);
    region_s[w][lane] = (char)(hb*3+wb);
  }
  __syncthreads();
  const int g = lane>>4, l15 = lane&15;
  const bool edge = (wy==15) || (wx==15);
  const float scl = scale6[h];
  const f32x4 zf = {0.f,0.f,0.f,0.f};

  short8 kf[4];
  #pragma unroll
  for (int mt=0; mt<4; ++mt){
    const long base = (long)lidx_s[w][mt*16+l15]*576 + 192 + h*32 + g*8;
    short8 r = *(const short8*)(qkv + base);
    float f[8]; float ss = 0.f;
    #pragma unroll
    for (int e=0;e<8;++e){ f[e] = b2f((u16)r[e]); ss += f[e]*f[e]; }
    ss += __shfl_xor(ss,16); ss += __shfl_xor(ss,32);
    const float inv = 1.0f/fmaxf(sqrtf(ss), 1e-12f);
    #pragma unroll
    for (int e=0;e<8;++e) kf[mt][e] = (short)f2b(f[e]*inv);
  }

  #pragma unroll
  for (int nt=0; nt<4; ++nt){
    short8 qf;
    {
      const long base = (long)lidx_s[w][nt*16+l15]*576 + h*32 + g*8;
      short8 r = *(const short8*)(qkv + base);
      float f[8]; float ss = 0.f;
      #pragma unroll
      for (int e=0;e<8;++e){ f[e] = b2f((u16)r[e]); ss += f[e]*f[e]; }
      ss += __shfl_xor(ss,16); ss += __shfl_xor(ss,32);
      const float inv = 1.0f/fmaxf(sqrtf(ss), 1e-12f);
      #pragma unroll
      for (int e=0;e<8;++e) qf[e] = (short)f2b(f[e]*inv);
    }
    f32x4 st[4];
    #pragma unroll
    for (int mt=0; mt<4; ++mt)
      st[mt] = __builtin_amdgcn_mfma_f32_16x16x32_bf16(kf[mt], qf, zf, 0, 0, 0);
    float lv[16];
    const float* rp = rpbL + ((h*4+nt)*4)*256 + lane*4;
    const int rq = edge ? region_s[w][nt*16+l15] : 0;
    #pragma unroll
    for (int mt=0; mt<4; ++mt){
      const f32x4 rb = *(const f32x4*)(rp + mt*256);
      #pragma unroll
      for (int i=0;i<4;++i){
        float v = st[mt][i]*scl + rb[i];
        if (edge && region_s[w][mt*16+g*4+i] != rq) v -= 100.0f;
        lv[mt*4+i] = v;
      }
    }
    float mx = lv[0];
    #pragma unroll
    for (int t=1;t<16;++t) mx = fmaxf(mx, lv[t]);
    mx = fmaxf(mx, __shfl_xor(mx,16)); mx = fmaxf(mx, __shfl_xor(mx,32));
    float sum = 0.f;
    #pragma unroll
    for (int t=0;t<16;++t){ lv[t] = __expf(lv[t]-mx); sum += lv[t]; }
    sum += __shfl_xor(sum,16); sum += __shfl_xor(sum,32);
    const float isum = 1.0f/sum;
    u16* pr = p_s[w] + (nt*16+l15)*72;
    #pragma unroll
    for (int mt=0; mt<4; ++mt){
      #pragma unroll
      for (int j=0;j<2;++j){
        unsigned lo = f2b(lv[mt*4+2*j]  *isum);
        unsigned hi = f2b(lv[mt*4+2*j+1]*isum);
        *(unsigned*)(pr + mt*16 + g*4 + 2*j) = lo | (hi<<16);
      }
    }
  }

  short8 vf[2][2];
  #pragma unroll
  for (int nd=0; nd<2; ++nd)
    #pragma unroll
    for (int kc=0; kc<2; ++kc)
      #pragma unroll
      for (int e=0;e<8;++e){
        const int tok = kc*32 + g*8 + e;
        vf[nd][kc][e] = (short)qkv[(long)lidx_s[w][tok]*576 + 384 + h*32 + nd*16 + l15];
      }

  __syncthreads();

  #pragma unroll
  for (int mt=0; mt<4; ++mt){
    const short8 a0 = *(const short8*)(p_s[w] + (mt*16+l15)*72 +      g*8);
    const short8 a1 = *(const short8*)(p_s[w] + (mt*16+l15)*72 + 32 + g*8);
    #pragma unroll
    for (int nd=0; nd<2; ++nd){
      f32x4 o = __builtin_amdgcn_mfma_f32_16x16x32_bf16(a0, vf[nd][0], zf, 0, 0, 0);
      o = __builtin_amdgcn_mfma_f32_16x16x32_bf16(a1, vf[nd][1], o, 0, 0, 0);
      #pragma unroll
      for (int i=0;i<4;++i){
        const int q = mt*16 + g*4 + i;
        aout[(long)lidx_s[w][q]*192 + h*32 + nd*16 + l15] = f2b(o[i]);
      }
    }
  }
}

// ---------------------------------------------------------------------------
extern "C" void kernel_launch(void* const* d_in, const int* in_sizes, int n_in,
                              void* d_out, int out_size, void* d_ws, size_t ws_size,
                              hipStream_t stream)
{
  const float* x     = (const float*)d_in[0];
  const float* n1w   = (const float*)d_in[3];
  const float* n1b   = (const float*)d_in[4];
  const float* qkvw  = (const float*)d_in[5];
  const float* qb    = (const float*)d_in[6];
  const float* vb    = (const float*)d_in[7];
  const float* lgs   = (const float*)d_in[8];
  const float* cpb1w = (const float*)d_in[9];
  const float* cpb1b = (const float*)d_in[10];
  const float* cpb2w = (const float*)d_in[11];
  const float* projw = (const float*)d_in[12];
  const float* projb = (const float*)d_in[13];
  const float* cab1w = (const float*)d_in[14];
  const float* cab1b = (const float*)d_in[15];
  const float* cab2w = (const float*)d_in[16];
  const float* cab2b = (const float*)d_in[17];
  const float* ca1w  = (const float*)d_in[18];
  const float* ca1b  = (const float*)d_in[19];
  const float* ca2w  = (const float*)d_in[20];
  const float* ca2b  = (const float*)d_in[21];
  const float* n2w   = (const float*)d_in[22];
  const float* n2b   = (const float*)d_in[23];
  const float* fc1w  = (const float*)d_in[24];
  const float* fc1b  = (const float*)d_in[25];
  const float* fc2w  = (const float*)d_in[26];
  const float* fc2b  = (const float*)d_in[27];
  float* dout = (float*)d_out;
  char* ws = (char*)d_ws;

  constexpr size_t OFF_XN  = 0;
  constexpr size_t OFF_G1  = 50331648;
  constexpr size_t OFF_C2  = 67108864;
  constexpr size_t OFF_AO  = 167772160;
  constexpr size_t OFF_QKV = 218103808;
  constexpr size_t OFF_X2N = OFF_QKV;
  constexpr size_t OFF_H1  = 0;
  constexpr size_t OFF_SM  = 369098752;

  u16*   xn      = (u16*)(ws + OFF_XN);
  u16*   g1      = (u16*)(ws + OFF_G1);
  float* c2      = (float*)(ws + OFF_C2);
  u16*   ao      = (u16*)(ws + OFF_AO);
  u16*   qkvb    = (u16*)(ws + OFF_QKV);
  u16*   x2n     = (u16*)(ws + OFF_X2N);
  u16*   h1      = (u16*)(ws + OFF_H1);
  float* qkvbias = (float*)(ws + OFF_SM);
  float* scale6  = (float*)(ws + OFF_SM + 4096);
  float* ssum    = (float*)(ws + OFF_SM + 8192);
  float* sgate   = (float*)(ws + OFF_SM + 16384);
  float* rpbL    = (float*)(ws + OFF_SM + 24576);
  u16*   wqkv    = (u16*)(ws + OFF_SM + 131072);
  u16*   wproj   = (u16*)(ws + OFF_SM + 360448);
  u16*   wfc1    = (u16*)(ws + OFF_SM + 434176);
  u16*   wfc2    = (u16*)(ws + OFF_SM + 729088);
  u16*   wt1     = (u16*)(ws + OFF_SM + 1024000);
  u16*   wt2     = (u16*)(ws + OFF_SM + 1245184);

  prep_k<<<2595, 256, 0, stream>>>(qkvw, qb, vb, projw, fc1w, fc2w, cab1w, cab2w,
                                   lgs, qkvbias, wqkv, wproj, wfc1, wfc2, wt1, wt2, scale6);
  rpb_k<<<1, 256, 0, stream>>>(cpb1w, cpb1b, cpb2w, rpbL);
  ln_k<<<32768, 256, 0, stream>>>(x, n1w, n1b, xn);
  hipMemsetAsync(ssum, 0, 1536*4, stream);
  // conv1: gelu(conv3x3(xn)) -> g1 (bf16), implicit GEMM
  gemm2_k<1,9,192,64,64><<<dim3(1,512), 256, 0, stream>>>(xn, wt1, cab1b,
      nullptr, nullptr, nullptr, nullptr, g1, nullptr);
  // conv2: conv3x3(g1) -> c2 (f32) + fused channel squeeze
  gemm2_k<2,9,64,192,96><<<dim3(2,512), 256, 0, stream>>>(g1, wt2, cab2b,
      nullptr, nullptr, nullptr, c2, nullptr, ssum);
  se_k<<<1, 256, 0, stream>>>(ssum, ca1w, ca1b, ca2w, ca2b, sgate);
  // qkv projection
  gemm2_k<0,1,192,576,96><<<dim3(6,512), 256, 0, stream>>>(xn, wqkv, qkvbias,
      nullptr, nullptr, nullptr, nullptr, qkvb, nullptr);
  attn_k<<<3072, 256, 0, stream>>>(qkvb, rpbL, scale6, ao);
  // proj + residual + CAB merge -> d_out
  gemm2_k<3,1,192,192,96><<<dim3(2,512), 256, 0, stream>>>(ao, wproj, projb,
      x, c2, sgate, dout, nullptr, nullptr);
  ln_k<<<32768, 256, 0, stream>>>(dout, n2w, n2b, x2n);
  // fc1 + gelu
  gemm2_k<4,1,192,768,96><<<dim3(8,512), 256, 0, stream>>>(x2n, wfc1, fc1b,
      nullptr, nullptr, nullptr, nullptr, h1, nullptr);
  // fc2 accumulate into d_out
  gemm2_k<5,1,768,192,96><<<dim3(2,512), 256, 0, stream>>>(h1, wfc2, fc2b,
      nullptr, nullptr, nullptr, dout, nullptr, nullptr);
}

// Round 4
// 868.085 us; speedup vs baseline: 1.0560x; 1.0560x over previous
//
#include <hip/hip_runtime.h>
#include <math.h>

// ---------------------------------------------------------------------------
// SwinV2-style block (DIM=192, HEADS=6, WS=8, SHIFT=4) on MI355X.
// Round 4: full-K-in-LDS GEMM (A staged once/block, N-panel loop), halo-LDS
// implicit-GEMM convs, c2 in bf16. Attention kernel unchanged (round 2).
// ---------------------------------------------------------------------------

typedef unsigned short u16;
typedef __attribute__((ext_vector_type(8))) short short8;
typedef __attribute__((ext_vector_type(4))) float f32x4;

#define DI static __device__ __forceinline__

DI float b2f(u16 u){ union{unsigned u; float f;} v; v.u = ((unsigned)u)<<16; return v.f; }
DI u16 f2b(float f){ union{float f; unsigned u;} v; v.f = f; unsigned r = v.u + 0x7fffu + ((v.u>>16)&1u); return (u16)(r>>16); }
DI float gelu_f(float x){ return 0.5f*x*(1.0f+erff(x*0.7071067811865475f)); }

// ---------------- LayerNorm: f32 in -> bf16 out (row = 192 ch) -------------
__global__ __launch_bounds__(256) void ln_k(const float* __restrict__ in,
    const float* __restrict__ w, const float* __restrict__ b, u16* __restrict__ out)
{
  const int row  = blockIdx.x*4 + (threadIdx.x>>6);
  const int lane = threadIdx.x & 63;
  const float* r = in + (long)row*192;
  float v0 = r[lane], v1 = r[lane+64], v2 = r[lane+128];
  float s = v0+v1+v2;
  #pragma unroll
  for (int m=1;m<64;m<<=1) s += __shfl_xor(s, m);
  float mu = s*(1.0f/192.0f);
  float d0=v0-mu, d1=v1-mu, d2=v2-mu;
  float q = d0*d0+d1*d1+d2*d2;
  #pragma unroll
  for (int m=1;m<64;m<<=1) q += __shfl_xor(q, m);
  float rstd = rsqrtf(q*(1.0f/192.0f)+1e-5f);
  u16* o = out + (long)row*192;
  o[lane]     = f2b(d0*rstd*w[lane]    +b[lane]);
  o[lane+64]  = f2b(d1*rstd*w[lane+64] +b[lane+64]);
  o[lane+128] = f2b(d2*rstd*w[lane+128]+b[lane+128]);
}

// ------------- weight prep: f32->bf16 + conv re-layout + qkv bias ----------
__global__ __launch_bounds__(256) void prep_k(
    const float* __restrict__ qkv_w, const float* __restrict__ q_bias,
    const float* __restrict__ v_bias, const float* __restrict__ proj_w,
    const float* __restrict__ fc1_w, const float* __restrict__ fc2_w,
    const float* __restrict__ cab1_w, const float* __restrict__ cab2_w,
    const float* __restrict__ lgs,
    float* __restrict__ qkvbias, u16* __restrict__ wqkv, u16* __restrict__ wproj,
    u16* __restrict__ wfc1, u16* __restrict__ wfc2, u16* __restrict__ wt1,
    u16* __restrict__ wt2, float* __restrict__ scale6)
{
  int o = blockIdx.x*256 + threadIdx.x;
  if (o < 576){ qkvbias[o] = (o<192)? q_bias[o] : ((o<384)? 0.f : v_bias[o-384]); return; }
  o -= 576;
  if (o < 110592){ wqkv[o] = f2b(qkv_w[o]); return; } o -= 110592;
  if (o < 36864){ wproj[o] = f2b(proj_w[o]); return; } o -= 36864;
  if (o < 147456){ wfc1[o] = f2b(fc1_w[o]); return; } o -= 147456;
  if (o < 147456){ wfc2[o] = f2b(fc2_w[o]); return; } o -= 147456;
  if (o < 110592){ // wt1[s][oc(64)][ic(192)] <- cab1_w[oc][ic][kh][kw]
    int s = o/12288, r = o%12288, oc = r/192, ic = r%192, kh = s/3, kw = s%3;
    wt1[o] = f2b(cab1_w[((oc*192+ic)*3+kh)*3+kw]); return; } o -= 110592;
  if (o < 110592){ // wt2[s][oc(192)][ic(64)] <- cab2_w[oc][ic][kh][kw]
    int s = o/12288, r = o%12288, oc = r/64, ic = r%64, kh = s/3, kw = s%3;
    wt2[o] = f2b(cab2_w[((oc*64+ic)*3+kh)*3+kw]); return; } o -= 110592;
  if (o < 6){ scale6[o] = expf(fminf(lgs[o], logf(100.f))); }
}

// ---- CPB MLP -> rpbL in MFMA C-fragment order: [h][nQ][mK][lane][i] -------
__global__ __launch_bounds__(256) void rpb_k(const float* __restrict__ w1,
    const float* __restrict__ b1, const float* __restrict__ w2, float* __restrict__ rpbL)
{
  __shared__ float hb[225*6];
  const int tid = threadIdx.x;
  if (tid < 225){
    int di = tid/15, dj = tid%15;
    float vi = (di-7)*(8.0f/7.0f), vj = (dj-7)*(8.0f/7.0f);
    float t0 = (vi==0.f)?0.f:copysignf(log2f(fabsf(vi)+1.f)*(1.f/3.f), vi);
    float t1 = (vj==0.f)?0.f:copysignf(log2f(fabsf(vj)+1.f)*(1.f/3.f), vj);
    float acc[6] = {0,0,0,0,0,0};
    for (int hd=0; hd<512; ++hd){
      float a = fmaxf(t0*w1[hd*2] + t1*w1[hd*2+1] + b1[hd], 0.f);
      #pragma unroll
      for (int h=0;h<6;++h) acc[h] += a*w2[h*512+hd];
    }
    #pragma unroll
    for (int h=0;h<6;++h) hb[tid*6+h] = acc[h];
  }
  __syncthreads();
  for (int o = tid; o < 24576; o += 256){
    int i = o&3, lane = (o>>2)&63, mK = (o>>8)&3, nQ = (o>>10)&3, h = o>>12;
    int q = nQ*16 + (lane&15), k = mK*16 + (lane>>4)*4 + i;
    int idx = ((q>>3)-(k>>3)+7)*15 + ((q&7)-(k&7)+7);
    rpbL[o] = 16.0f/(1.0f+expf(-hb[idx*6+h]));
  }
}

// ----------------- epilogue helper for gemm3 -------------------------------
template<int EPI, int NN>
DI void epilog3(f32x4 (&acc)[2][4], int m0, int w, int lane, int n0,
                const float* __restrict__ bias, const float* __restrict__ resx,
                const u16* __restrict__ c2in, const float* __restrict__ sgate,
                float* __restrict__ outf, u16* __restrict__ outb)
{
  const int fr = lane&15, g = lane>>4;
  #pragma unroll
  for (int mr=0;mr<2;++mr){
    #pragma unroll
    for (int nr=0;nr<4;++nr){
      const int gcol = n0 + nr*16 + fr;
      const float bcol = bias[gcol];
      #pragma unroll
      for (int i=0;i<4;++i){
        const int grow = m0 + w*32 + mr*16 + g*4 + i;
        const long o = (long)grow*NN + gcol;
        float v = acc[mr][nr][i] + bcol;
        if constexpr (EPI==0){ outb[o] = f2b(v); }                      // qkv
        else if constexpr (EPI==3){                                     // proj merge
          outf[o] = v + resx[o] + 0.01f*b2f(c2in[o])*sgate[(grow>>14)*192 + gcol];
        }
        else if constexpr (EPI==4){ outb[o] = f2b(gelu_f(v)); }         // fc1
        else { outf[o] = outf[o] + v; }                                 // fc2 +=
      }
    }
  }
}

// ------- gemm3: out(M,NN) = A(M,KK) @ W(NN,KK)^T, full-K(192-chunk) LDS ----
// Block = 128 rows, 4 waves (wave = 32 rows x 64-col panel). A staged once
// per 192-K-chunk (padded rows: conflict-free b128 frags), B per 64-panel.
template<int EPI, int KK, int NN>
__global__ __launch_bounds__(256) void gemm3_k(
    const u16* __restrict__ A, const u16* __restrict__ W,
    const float* __restrict__ bias, const float* __restrict__ resx,
    const u16* __restrict__ c2in, const float* __restrict__ sgate,
    float* __restrict__ outf, u16* __restrict__ outb)
{
  constexpr int KC = KK/192;
  constexpr int NP = NN/64;
  __shared__ __align__(16) u16 As[128*200];
  __shared__ __align__(16) u16 Bs[64*200];
  const int tid = threadIdx.x, w = tid>>6, lane = tid&63;
  const int fr = lane&15, g = lane>>4;
  const int m0 = blockIdx.x*128;

  #define STAGE_A(kc) { \
    _Pragma("unroll") \
    for (int i=0;i<12;++i){ const int id=tid+i*256, row=id/24, cc=id%24; \
      *(short8*)&As[row*200+cc*8] = \
        *(const short8*)(A + (long)(m0+row)*KK + (kc)*192 + cc*8); } }
  #define STAGE_B(n0,kc) { \
    _Pragma("unroll") \
    for (int i=0;i<6;++i){ const int id=tid+i*256, br=id/24, cc=id%24; \
      *(short8*)&Bs[br*200+cc*8] = \
        *(const short8*)(W + (long)((n0)+br)*KK + (kc)*192 + cc*8); } }
  #define KLOOP(accr) { \
    _Pragma("unroll") \
    for (int ks=0; ks<6; ++ks){ \
      short8 af0 = *(const short8*)&As[(w*32+     fr)*200 + ks*32 + g*8]; \
      short8 af1 = *(const short8*)&As[(w*32+16+  fr)*200 + ks*32 + g*8]; \
      _Pragma("unroll") \
      for (int nr=0;nr<4;++nr){ \
        short8 bf = *(const short8*)&Bs[(nr*16+fr)*200 + ks*32 + g*8]; \
        accr[0][nr] = __builtin_amdgcn_mfma_f32_16x16x32_bf16(af0, bf, accr[0][nr], 0,0,0); \
        accr[1][nr] = __builtin_amdgcn_mfma_f32_16x16x32_bf16(af1, bf, accr[1][nr], 0,0,0); \
      } } }

  if constexpr (KC == 1){
    STAGE_A(0);
    for (int p=0; p<NP; ++p){
      const int n0 = p*64;
      __syncthreads();                 // Bs reuse + (first iter) As visibility
      STAGE_B(n0, 0);
      __syncthreads();
      f32x4 acc[2][4];
      #pragma unroll
      for (int a=0;a<2;++a)
        #pragma unroll
        for (int b=0;b<4;++b) acc[a][b] = (f32x4){0.f,0.f,0.f,0.f};
      KLOOP(acc);
      epilog3<EPI,NN>(acc, m0, w, lane, n0, bias, resx, c2in, sgate, outf, outb);
    }
  } else {
    f32x4 acc[NP][2][4];
    #pragma unroll
    for (int p=0;p<NP;++p)
      #pragma unroll
      for (int a=0;a<2;++a)
        #pragma unroll
        for (int b=0;b<4;++b) acc[p][a][b] = (f32x4){0.f,0.f,0.f,0.f};
    for (int kc=0; kc<KC; ++kc){
      __syncthreads();                 // As+Bs reuse from previous chunk
      STAGE_A(kc);
      #pragma unroll
      for (int p=0;p<NP;++p){
        __syncthreads();
        STAGE_B(p*64, kc);
        __syncthreads();
        KLOOP(acc[p]);
      }
    }
    #pragma unroll
    for (int p=0;p<NP;++p)
      epilog3<EPI,NN>(acc[p], m0, w, lane, p*64, bias, resx, c2in, sgate, outf, outb);
  }
  #undef STAGE_A
  #undef STAGE_B
  #undef KLOOP
}

// ------- conv3x3 implicit GEMM, halo in LDS, weights gathered from L2 ------
// Block = one image row (128 tokens) of one batch; 4 waves = 32 tokens each.
// CG channel-groups of 64 (conv1: 3, conv2: 1); taps are LDS offsets.
// EPI 1: gelu->bf16 (conv1, OC=64). EPI 2: ->bf16 c2 + fused squeeze (OC=192).
template<int EPI, int CG, int SC, int OC>
__global__ __launch_bounds__(256) void conv_k(
    const u16* __restrict__ A, const u16* __restrict__ W,
    const float* __restrict__ bias, u16* __restrict__ outb,
    float* __restrict__ ssum)
{
  constexpr int NR = OC/16;
  __shared__ __align__(16) u16 Ah[390*72];
  const int tid = threadIdx.x, w = tid>>6, lane = tid&63;
  const int fr = lane&15, g = lane>>4;
  const int blk = blockIdx.x;              // blk = b*128 + y0
  const int b = blk>>7, y0 = blk&127;

  f32x4 acc[2][NR];
  #pragma unroll
  for (int a=0;a<2;++a)
    #pragma unroll
    for (int n=0;n<NR;++n) acc[a][n] = (f32x4){0.f,0.f,0.f,0.f};

  for (int cg=0; cg<CG; ++cg){
    __syncthreads();                       // Ah reuse from previous group
    #pragma unroll
    for (int i=0;i<12;++i){                // 3 planes x 128 cols x 64ch
      const int id = tid + i*256, tok = id>>3, cc = id&7;
      const int p = tok>>7, x = tok&127, y = y0 + p - 1;
      short8 v = {0,0,0,0,0,0,0,0};
      if ((unsigned)y < 128u)
        v = *(const short8*)(A + (long)((((b<<7)|y)<<7)|x)*SC + cg*64 + cc*8);
      *(short8*)&Ah[((p*130)+(x+1))*72 + cc*8] = v;
    }
    if (tid < 48){                         // zero x-halo columns
      const int p = tid>>4, rr = tid&15, col = (rr>>3)?129:0, cc = rr&7;
      *(short8*)&Ah[((p*130)+col)*72 + cc*8] = (short8){0,0,0,0,0,0,0,0};
    }
    __syncthreads();
    #pragma unroll 3
    for (int tap=0; tap<9; ++tap){
      const int dy = tap/3, dx = tap%3;    // 0..2 => -1..+1 (halo offset built in)
      #pragma unroll
      for (int ks=0; ks<2; ++ks){
        short8 af[2];
        #pragma unroll
        for (int mr=0;mr<2;++mr){
          const int x = w*32 + mr*16 + fr;
          af[mr] = *(const short8*)&Ah[((dy*130)+(x+dx))*72 + ks*32 + g*8];
        }
        #pragma unroll
        for (int nr=0;nr<NR;++nr){
          const short8 bf = *(const short8*)(W +
              ((long)(tap*OC + nr*16 + fr))*(CG*64) + cg*64 + ks*32 + g*8);
          acc[0][nr] = __builtin_amdgcn_mfma_f32_16x16x32_bf16(af[0], bf, acc[0][nr], 0,0,0);
          acc[1][nr] = __builtin_amdgcn_mfma_f32_16x16x32_bf16(af[1], bf, acc[1][nr], 0,0,0);
        }
      }
    }
  }

  // ---- epilogue ----
  float cs[NR];
  #pragma unroll
  for (int n=0;n<NR;++n) cs[n] = 0.f;
  #pragma unroll
  for (int mr=0;mr<2;++mr){
    #pragma unroll
    for (int nr=0;nr<NR;++nr){
      const int oc = nr*16 + fr;
      const float bcol = bias[oc];
      #pragma unroll
      for (int i=0;i<4;++i){
        const int x = w*32 + mr*16 + g*4 + i;
        const long o = (long)(blk*128 + x)*OC + oc;
        float v = acc[mr][nr][i] + bcol;
        if constexpr (EPI==1){ outb[o] = f2b(gelu_f(v)); }
        else { outb[o] = f2b(v); cs[nr] += v; }
      }
    }
  }
  if constexpr (EPI==2){
    #pragma unroll
    for (int nr=0;nr<NR;++nr){
      float s = cs[nr];
      s += __shfl_xor(s,16); s += __shfl_xor(s,32);
      if (lane < 16) atomicAdd(&ssum[b*192 + nr*16 + lane], s);
    }
  }
}

// ------------- SE MLP ------------------------------------------------------
__global__ __launch_bounds__(256) void se_k(const float* __restrict__ ssum,
    const float* __restrict__ ca1w, const float* __restrict__ ca1b,
    const float* __restrict__ ca2w, const float* __restrict__ ca2b,
    float* __restrict__ sgate)
{
  __shared__ float hid[48];
  const int tid = threadIdx.x;
  if (tid < 48){
    int b = tid/6, cs = tid%6;
    float a = ca1b[cs];
    for (int c=0;c<192;++c) a += ssum[b*192+c]*(1.f/16384.f)*ca1w[cs*192+c];
    hid[tid] = fmaxf(a, 0.f);
  }
  __syncthreads();
  for (int o = tid; o < 1536; o += 256){
    int b = o/192, c = o%192;
    float a = ca2b[c];
    #pragma unroll
    for (int cs=0;cs<6;++cs) a += hid[b*6+cs]*ca2w[c*6+cs];
    sgate[o] = 1.f/(1.f+expf(-a));
  }
}

// ---------- MFMA windowed attention: 1 wave = 1 (window, head) -------------
__global__ __launch_bounds__(256) void attn_k(const u16* __restrict__ qkv,
    const float* __restrict__ rpbL, const float* __restrict__ scale6,
    u16* __restrict__ aout)
{
  __shared__ int  lidx_s[4][64];
  __shared__ char region_s[4][64];
  __shared__ __align__(16) u16 p_s[4][64*72];
  const int tid = threadIdx.x, w = tid>>6, lane = tid&63;
  const int task = blockIdx.x*4 + w;
  const int win = task/6, h = task - win*6;
  const int b = win>>8, wn = win&255, wy = wn>>4, wx = wn&15;
  {
    int i = lane>>3, j = lane&7;
    int hs = wy*8+i, ws = wx*8+j;
    lidx_s[w][lane] = (b<<14) | (((hs+4)&127)<<7) | ((ws+4)&127);
    int hb = hs<120?0:(hs<124?1:2), wb = ws<120?0:(ws<124?1:2);
    region_s[w][lane] = (char)(hb*3+wb);
  }
  __syncthreads();
  const int g = lane>>4, l15 = lane&15;
  const bool edge = (wy==15) || (wx==15);
  const float scl = scale6[h];
  const f32x4 zf = {0.f,0.f,0.f,0.f};

  short8 kf[4];
  #pragma unroll
  for (int mt=0; mt<4; ++mt){
    const long base = (long)lidx_s[w][mt*16+l15]*576 + 192 + h*32 + g*8;
    short8 r = *(const short8*)(qkv + base);
    float f[8]; float ss = 0.f;
    #pragma unroll
    for (int e=0;e<8;++e){ f[e] = b2f((u16)r[e]); ss += f[e]*f[e]; }
    ss += __shfl_xor(ss,16); ss += __shfl_xor(ss,32);
    const float inv = 1.0f/fmaxf(sqrtf(ss), 1e-12f);
    #pragma unroll
    for (int e=0;e<8;++e) kf[mt][e] = (short)f2b(f[e]*inv);
  }

  #pragma unroll
  for (int nt=0; nt<4; ++nt){
    short8 qf;
    {
      const long base = (long)lidx_s[w][nt*16+l15]*576 + h*32 + g*8;
      short8 r = *(const short8*)(qkv + base);
      float f[8]; float ss = 0.f;
      #pragma unroll
      for (int e=0;e<8;++e){ f[e] = b2f((u16)r[e]); ss += f[e]*f[e]; }
      ss += __shfl_xor(ss,16); ss += __shfl_xor(ss,32);
      const float inv = 1.0f/fmaxf(sqrtf(ss), 1e-12f);
      #pragma unroll
      for (int e=0;e<8;++e) qf[e] = (short)f2b(f[e]*inv);
    }
    f32x4 st[4];
    #pragma unroll
    for (int mt=0; mt<4; ++mt)
      st[mt] = __builtin_amdgcn_mfma_f32_16x16x32_bf16(kf[mt], qf, zf, 0, 0, 0);
    float lv[16];
    const float* rp = rpbL + ((h*4+nt)*4)*256 + lane*4;
    const int rq = edge ? region_s[w][nt*16+l15] : 0;
    #pragma unroll
    for (int mt=0; mt<4; ++mt){
      const f32x4 rb = *(const f32x4*)(rp + mt*256);
      #pragma unroll
      for (int i=0;i<4;++i){
        float v = st[mt][i]*scl + rb[i];
        if (edge && region_s[w][mt*16+g*4+i] != rq) v -= 100.0f;
        lv[mt*4+i] = v;
      }
    }
    float mx = lv[0];
    #pragma unroll
    for (int t=1;t<16;++t) mx = fmaxf(mx, lv[t]);
    mx = fmaxf(mx, __shfl_xor(mx,16)); mx = fmaxf(mx, __shfl_xor(mx,32));
    float sum = 0.f;
    #pragma unroll
    for (int t=0;t<16;++t){ lv[t] = __expf(lv[t]-mx); sum += lv[t]; }
    sum += __shfl_xor(sum,16); sum += __shfl_xor(sum,32);
    const float isum = 1.0f/sum;
    u16* pr = p_s[w] + (nt*16+l15)*72;
    #pragma unroll
    for (int mt=0; mt<4; ++mt){
      #pragma unroll
      for (int j=0;j<2;++j){
        unsigned lo = f2b(lv[mt*4+2*j]  *isum);
        unsigned hi = f2b(lv[mt*4+2*j+1]*isum);
        *(unsigned*)(pr + mt*16 + g*4 + 2*j) = lo | (hi<<16);
      }
    }
  }

  short8 vf[2][2];
  #pragma unroll
  for (int nd=0; nd<2; ++nd)
    #pragma unroll
    for (int kc=0; kc<2; ++kc)
      #pragma unroll
      for (int e=0;e<8;++e){
        const int tok = kc*32 + g*8 + e;
        vf[nd][kc][e] = (short)qkv[(long)lidx_s[w][tok]*576 + 384 + h*32 + nd*16 + l15];
      }

  __syncthreads();

  #pragma unroll
  for (int mt=0; mt<4; ++mt){
    const short8 a0 = *(const short8*)(p_s[w] + (mt*16+l15)*72 +      g*8);
    const short8 a1 = *(const short8*)(p_s[w] + (mt*16+l15)*72 + 32 + g*8);
    #pragma unroll
    for (int nd=0; nd<2; ++nd){
      f32x4 o = __builtin_amdgcn_mfma_f32_16x16x32_bf16(a0, vf[nd][0], zf, 0, 0, 0);
      o = __builtin_amdgcn_mfma_f32_16x16x32_bf16(a1, vf[nd][1], o, 0, 0, 0);
      #pragma unroll
      for (int i=0;i<4;++i){
        const int q = mt*16 + g*4 + i;
        aout[(long)lidx_s[w][q]*192 + h*32 + nd*16 + l15] = f2b(o[i]);
      }
    }
  }
}

// ---------------------------------------------------------------------------
extern "C" void kernel_launch(void* const* d_in, const int* in_sizes, int n_in,
                              void* d_out, int out_size, void* d_ws, size_t ws_size,
                              hipStream_t stream)
{
  const float* x     = (const float*)d_in[0];
  const float* n1w   = (const float*)d_in[3];
  const float* n1b   = (const float*)d_in[4];
  const float* qkvw  = (const float*)d_in[5];
  const float* qb    = (const float*)d_in[6];
  const float* vb    = (const float*)d_in[7];
  const float* lgs   = (const float*)d_in[8];
  const float* cpb1w = (const float*)d_in[9];
  const float* cpb1b = (const float*)d_in[10];
  const float* cpb2w = (const float*)d_in[11];
  const float* projw = (const float*)d_in[12];
  const float* projb = (const float*)d_in[13];
  const float* cab1w = (const float*)d_in[14];
  const float* cab1b = (const float*)d_in[15];
  const float* cab2w = (const float*)d_in[16];
  const float* cab2b = (const float*)d_in[17];
  const float* ca1w  = (const float*)d_in[18];
  const float* ca1b  = (const float*)d_in[19];
  const float* ca2w  = (const float*)d_in[20];
  const float* ca2b  = (const float*)d_in[21];
  const float* n2w   = (const float*)d_in[22];
  const float* n2b   = (const float*)d_in[23];
  const float* fc1w  = (const float*)d_in[24];
  const float* fc1b  = (const float*)d_in[25];
  const float* fc2w  = (const float*)d_in[26];
  const float* fc2b  = (const float*)d_in[27];
  float* dout = (float*)d_out;
  char* ws = (char*)d_ws;

  constexpr size_t OFF_XN  = 0;                  // bf16 131072*192 (dead after qkv)
  constexpr size_t OFF_G1  = 50331648;           // bf16 131072*64  (dead after conv2)
  constexpr size_t OFF_C2  = 67108864;           // bf16 131072*192 (dead after proj)
  constexpr size_t OFF_AO  = 167772160;          // bf16 131072*192 (dead after proj)
  constexpr size_t OFF_QKV = 218103808;          // bf16 131072*576 (dead after attn)
  constexpr size_t OFF_X2N = OFF_QKV;            // bf16 131072*192 (aliases qkv)
  constexpr size_t OFF_H1  = 0;                  // bf16 131072*768 (aliases xn..ao)
  constexpr size_t OFF_SM  = 369098752;

  u16*   xn      = (u16*)(ws + OFF_XN);
  u16*   g1      = (u16*)(ws + OFF_G1);
  u16*   c2      = (u16*)(ws + OFF_C2);
  u16*   ao      = (u16*)(ws + OFF_AO);
  u16*   qkvb    = (u16*)(ws + OFF_QKV);
  u16*   x2n     = (u16*)(ws + OFF_X2N);
  u16*   h1      = (u16*)(ws + OFF_H1);
  float* qkvbias = (float*)(ws + OFF_SM);
  float* scale6  = (float*)(ws + OFF_SM + 4096);
  float* ssum    = (float*)(ws + OFF_SM + 8192);
  float* sgate   = (float*)(ws + OFF_SM + 16384);
  float* rpbL    = (float*)(ws + OFF_SM + 24576);
  u16*   wqkv    = (u16*)(ws + OFF_SM + 131072);
  u16*   wproj   = (u16*)(ws + OFF_SM + 360448);
  u16*   wfc1    = (u16*)(ws + OFF_SM + 434176);
  u16*   wfc2    = (u16*)(ws + OFF_SM + 729088);
  u16*   wt1     = (u16*)(ws + OFF_SM + 1024000);
  u16*   wt2     = (u16*)(ws + OFF_SM + 1245184);

  prep_k<<<2595, 256, 0, stream>>>(qkvw, qb, vb, projw, fc1w, fc2w, cab1w, cab2w,
                                   lgs, qkvbias, wqkv, wproj, wfc1, wfc2, wt1, wt2, scale6);
  rpb_k<<<1, 256, 0, stream>>>(cpb1w, cpb1b, cpb2w, rpbL);
  ln_k<<<32768, 256, 0, stream>>>(x, n1w, n1b, xn);
  hipMemsetAsync(ssum, 0, 1536*4, stream);
  // conv1: gelu(conv3x3(xn)) -> g1 (bf16)
  conv_k<1,3,192,64><<<1024, 256, 0, stream>>>(xn, wt1, cab1b, g1, nullptr);
  // conv2: conv3x3(g1) -> c2 (bf16) + fused squeeze
  conv_k<2,1,64,192><<<1024, 256, 0, stream>>>(g1, wt2, cab2b, c2, ssum);
  se_k<<<1, 256, 0, stream>>>(ssum, ca1w, ca1b, ca2w, ca2b, sgate);
  // qkv projection -> qkvb (bf16)
  gemm3_k<0,192,576><<<1024, 256, 0, stream>>>(xn, wqkv, qkvbias,
      nullptr, nullptr, nullptr, nullptr, qkvb);
  attn_k<<<3072, 256, 0, stream>>>(qkvb, rpbL, scale6, ao);
  // proj + residual + CAB merge -> d_out (f32)
  gemm3_k<3,192,192><<<1024, 256, 0, stream>>>(ao, wproj, projb,
      x, c2, sgate, dout, nullptr);
  ln_k<<<32768, 256, 0, stream>>>(dout, n2w, n2b, x2n);
  // fc1 + gelu -> h1 (bf16)
  gemm3_k<4,192,768><<<1024, 256, 0, stream>>>(x2n, wfc1, fc1b,
      nullptr, nullptr, nullptr, nullptr, h1);
  // fc2 accumulate into d_out
  gemm3_k<5,768,192><<<1024, 256, 0, stream>>>(h1, wfc2, fc2b,
      nullptr, nullptr, nullptr, dout, nullptr);
}